// Round 8
// baseline (521.879 us; speedup 1.0000x reference)
//
#include <hip/hip_runtime.h>
#include <hip/hip_bf16.h>
#include <hip/hip_cooperative_groups.h>
#include <math.h>

namespace cg = cooperative_groups;

// Problem constants
#define FPD 96      // frame size
#define DPD 28      // digit/kernel size
#define CPD 69      // FPD - DPD + 1
#define NPD 4761    // CPD*CPD
#define KKC 3       // K iterations
#define SBN 256     // S*B images
#define TT 8        // T
#define HD 512      // H
#define KPAD 5120   // 8*640, padded K for MFMA GEMM
#define SPLITK 8
#define FRSH 104    // frame LDS row stride (halfs)
#define CVS 76      // cv slab row stride (floats)

typedef __attribute__((ext_vector_type(8))) short bf16x8;
typedef __attribute__((ext_vector_type(4))) float f32x4;
typedef _Float16 half_t;
typedef __attribute__((ext_vector_type(2))) _Float16 half2_t;

__device__ __forceinline__ float bf2f_lo(unsigned int u) {
    union { unsigned int i; float f; } v; v.i = u << 16; return v.f;
}
__device__ __forceinline__ float bf2f_hi(unsigned int u) {
    union { unsigned int i; float f; } v; v.i = u & 0xffff0000u; return v.f;
}
__device__ __forceinline__ half2_t u2h(unsigned int u) {
    union { unsigned int i; half2_t h; } v; v.i = u; return v.h;
}
__device__ __forceinline__ ushort f2bf(float f) {
    __hip_bfloat16 h = __float2bfloat16(f);
    return *reinterpret_cast<ushort*>(&h);
}

// ---------------------------------------------------------------------------
// One cooperative kernel: weight prep, then 3x (conv+softmax -> gemm -> mlp)
// with grid.sync() between cross-block phases. 256 blocks x 1024 threads,
// 1 block/CU co-resident. LDS arena reused by every phase.
__global__ __launch_bounds__(1024, 4) void mega_kernel(
    const float* __restrict__ frames, const float* __restrict__ ck,
    const float* __restrict__ eps, const float* __restrict__ W1,
    const float* __restrict__ b1,
    const float* __restrict__ Wm1, const float* __restrict__ bm1,
    const float* __restrict__ Wm2, const float* __restrict__ bm2,
    const float* __restrict__ Ws1, const float* __restrict__ bs1,
    const float* __restrict__ Ws2, const float* __restrict__ bs2,
    const int* __restrict__ tsp, float* __restrict__ out,
    float* __restrict__ frameL, float* __restrict__ Cpart,
    float* __restrict__ inv_denom, float* __restrict__ z_cur,
    ushort* __restrict__ e_buf, ushort* __restrict__ W1T,
    ushort* __restrict__ WhidT)
{
    __shared__ __align__(16) char arena[108928];
    cg::grid_group grid = cg::this_grid();
    const int t = threadIdx.x;
    const int b = blockIdx.x;
    const int ib = b;                 // image for conv/mlp phases

    // ================= Phase P: weight prep =================
    {
        const int g = t >> 8, t2 = t & 255;
        const int ln = t2 & 63, lr = t2 >> 6;
        ushort (*tile)[65] = (ushort(*)[65])(arena + g * 8320);
        const int job = b * 4 + g;
        if (job < 640) {
            const int k0 = (job % 80) * 64;
            const int n0 = (job / 80) * 64;
            #pragma unroll
            for (int i = 0; i < 16; ++i) {
                int kk = k0 + lr + i * 4;
                float v = (kk < NPD) ? W1[(size_t)kk * HD + n0 + ln] : 0.f;
                tile[lr + i * 4][ln] = f2bf(v);
            }
        } else if (job < 704) {
            const int j2 = job - 640;
            const int i0 = (j2 & 7) * 64;
            const int r0 = (j2 >> 3) * 64;
            #pragma unroll
            for (int rep = 0; rep < 16; ++rep) {
                int i = i0 + lr + rep * 4;
                int r = r0 + ln;
                const float* src = (r >= 256) ? Ws1 : Wm1;
                tile[lr + rep * 4][ln] = f2bf(src[(size_t)i * 256 + (r & 255)]);
            }
        }
        __syncthreads();
        if (job < 640) {
            const int k0 = (job % 80) * 64;
            const int n0 = (job / 80) * 64;
            #pragma unroll
            for (int i = 0; i < 16; ++i) {
                int nn = lr + i * 4;
                W1T[(size_t)(n0 + nn) * KPAD + k0 + ln] = tile[ln][nn];
            }
        } else if (job < 704) {
            const int j2 = job - 640;
            const int i0 = (j2 & 7) * 64;
            const int r0 = (j2 >> 3) * 64;
            #pragma unroll
            for (int rep = 0; rep < 16; ++rep) {
                int r = r0 + lr + rep * 4;
                WhidT[(size_t)r * 512 + i0 + ln] = tile[ln][lr + rep * 4];
            }
        }
        __syncthreads();
    }

    for (int k = 0; k < KKC; ++k) {
        // ================= Phase A: conv + recon + softmax-exp =================
        {
            half_t* fr  = (half_t*)arena;                 // 96*104 halfs
            half_t* kr  = (half_t*)(arena + 19968);       // 28*32 halfs
            float*  dgp = (float*)(arena + 21760);        // 784 f
            float*  cvb = (float*)(arena + 24896);        // 4 * 69*76 f
            float*  red = (float*)(arena + 108800);       // 32 f

            if (t < 28 * 32) {
                int dy = t >> 5, dx = t & 31;
                float v = (dx < 28) ? ck[((size_t)ib * KKC + k) * 784 + dy * 28 + dx] : 0.f;
                kr[t] = (half_t)v;
            }
            if (k > 0 && t < 784) dgp[t] = ck[((size_t)ib * KKC + (k - 1)) * 784 + t];
            float zx = 0.f, zy = 0.f;
            if (k > 0) { zx = z_cur[ib * 2]; zy = z_cur[ib * 2 + 1]; }
            __syncthreads();

            const float* src = (k < 2)
                ? frames + ((size_t)ib * TT + *tsp) * 9216
                : frameL + (size_t)ib * 9216;
            const float scale = 96.f / 28.f;
            for (int p = t; p < 9216; p += 1024) {
                int r = p / 96, c = p - r * 96;
                float val = src[p];
                if (k > 0) {
                    float oci = (2.f * r + 1.f) / 96.f - 1.f;
                    float ocj = (2.f * c + 1.f) / 96.f - 1.f;
                    float py = ((scale * (oci - zy) + 1.f) * 28.f - 1.f) * 0.5f;
                    float px = ((scale * (ocj - zx) + 1.f) * 28.f - 1.f) * 0.5f;
                    float py0f = floorf(py), px0f = floorf(px);
                    float fy = py - py0f, fx = px - px0f;
                    int y0 = (int)py0f, x0 = (int)px0f;
                    int y1 = y0 + 1, x1 = x0 + 1;
                    float wy0 = (y0 >= 0 && y0 < DPD) ? 1.f - fy : 0.f;
                    float wy1 = (y1 >= 0 && y1 < DPD) ? fy : 0.f;
                    float wx0 = (x0 >= 0 && x0 < DPD) ? 1.f - fx : 0.f;
                    float wx1 = (x1 >= 0 && x1 < DPD) ? fx : 0.f;
                    int y0c = min(max(y0, 0), DPD - 1), y1c = min(max(y1, 0), DPD - 1);
                    int x0c = min(max(x0, 0), DPD - 1), x1c = min(max(x1, 0), DPD - 1);
                    float tmp0 = wy0 * dgp[y0c * DPD + x0c] + wy1 * dgp[y1c * DPD + x0c];
                    float tmp1 = wy0 * dgp[y0c * DPD + x1c] + wy1 * dgp[y1c * DPD + x1c];
                    val -= wx0 * tmp0 + wx1 * tmp1;
                }
                fr[r * FRSH + c] = (half_t)val;
                if (k == 1) frameL[(size_t)ib * 9216 + p] = val;
            }
            if (t < 96 * 8) fr[(t >> 3) * FRSH + 96 + (t & 7)] = (half_t)0.f;
            __syncthreads();

            if (t < 828) {
                const int q    = t / 207;
                const int rem  = t - q * 207;
                const int tile = rem / 69;
                const int oy   = rem - tile * 69;
                const int ox0  = tile * 24;
                const int dy0  = q * 7;

                float acc[24];
                #pragma unroll
                for (int j = 0; j < 24; ++j) acc[j] = 0.f;

                #pragma unroll 1
                for (int dd = 0; dd < 7; ++dd) {
                    const int dy = dy0 + dd;
                    const unsigned int* frow = (const unsigned int*)&fr[(oy + dy) * FRSH + ox0];
                    const unsigned int* krow = (const unsigned int*)&kr[dy * 32];
                    unsigned int W[28], K[16], V[25];
                    #pragma unroll
                    for (int u = 0; u < 7; ++u) {
                        uint4 v = *(const uint4*)(frow + 4 * u);
                        W[4*u] = v.x; W[4*u+1] = v.y; W[4*u+2] = v.z; W[4*u+3] = v.w;
                    }
                    #pragma unroll
                    for (int u = 0; u < 4; ++u) {
                        uint4 v = *(const uint4*)(krow + 4 * u);
                        K[4*u] = v.x; K[4*u+1] = v.y; K[4*u+2] = v.z; K[4*u+3] = v.w;
                    }
                    #pragma unroll
                    for (int i = 0; i < 25; ++i)
                        V[i] = (W[i] >> 16) | (W[i + 1] << 16);
                    #pragma unroll
                    for (int m = 0; m < 12; ++m) {
                        float ae = acc[2*m], ao = acc[2*m+1];
                        #pragma unroll
                        for (int i = 0; i < 14; ++i) {
                            ae = __builtin_amdgcn_fdot2(u2h(W[m + i]), u2h(K[i]), ae, false);
                            ao = __builtin_amdgcn_fdot2(u2h(V[m + i]), u2h(K[i]), ao, false);
                        }
                        acc[2*m] = ae; acc[2*m+1] = ao;
                    }
                }
                float* cvq = cvb + q * 5244 + oy * CVS + ox0;
                #pragma unroll
                for (int u = 0; u < 6; ++u) {
                    float4 v = make_float4(acc[4*u], acc[4*u+1], acc[4*u+2], acc[4*u+3]);
                    *(float4*)(cvq + 4 * u) = v;
                }
            }
            __syncthreads();

            // merge quarters + block max
            float m = -INFINITY;
            for (int p = t; p < 69 * CVS; p += 1024) {
                int ox = p - (p / CVS) * CVS;
                if (ox < CPD) {
                    float v = cvb[p] + cvb[5244 + p] + cvb[2*5244 + p] + cvb[3*5244 + p];
                    cvb[p] = v;
                    m = fmaxf(m, v);
                }
            }
            #pragma unroll
            for (int off = 32; off > 0; off >>= 1) m = fmaxf(m, __shfl_down(m, off, 64));
            int lane = t & 63, wid = t >> 6;
            if (lane == 0) red[wid] = m;
            __syncthreads();
            m = red[0];
            #pragma unroll
            for (int i = 1; i < 16; ++i) m = fmaxf(m, red[i]);

            float s = 0.f;
            ushort* eo = e_buf + (size_t)ib * KPAD;
            for (int p = t; p < 69 * CVS; p += 1024) {
                int oy = p / CVS;
                int ox = p - oy * CVS;
                if (ox < CPD) {
                    float ev = __expf(cvb[p] - m);
                    eo[oy * CPD + ox] = f2bf(ev);
                    s += ev;
                }
            }
            #pragma unroll
            for (int off = 32; off > 0; off >>= 1) s += __shfl_down(s, off, 64);
            if (lane == 0) red[16 + wid] = s;
            __syncthreads();
            if (t == 0) {
                float tot = 0.f;
                #pragma unroll
                for (int i = 0; i < 16; ++i) tot += red[16 + i];
                inv_denom[ib] = 1.0f / tot;
            }
            if (t < KPAD - NPD) eo[NPD + t] = 0;   // zero k-padding (359)
        }

        grid.sync();

        // ================= Phase B: MFMA GEMM (64x64 tiles, splitK=8) =========
        {
            ushort* As = (ushort*)arena;          // 64 x 72 halfs
            ushort* Bs = As + 4608;               // 64 x 72 halfs

            const int m0 = (b & 3) * 64;
            const int n0 = ((b >> 2) & 7) * 64;
            const int z  = b >> 5;                // 0..7
            const int kbase = z * 640;

            const int l  = t & 63, w = t >> 6;    // 16 waves
            const int wm = w & 3, wn = w >> 2;
            const int lm = l & 15, kb = l >> 4;

            const int sr = (t & 511) >> 3;        // staging row 0..63
            const int sc = (t & 7) * 8;           // staging col (halfs)
            const ushort* gsrc = (t < 512)
                ? e_buf + (size_t)(m0 + sr) * KPAD + sc
                : W1T   + (size_t)(n0 + sr) * KPAD + sc;
            ushort* ldst = As + (t < 512 ? 0 : 4608) + sr * 72 + sc;

            f32x4 acc = {0.f, 0.f, 0.f, 0.f};
            float4 av = *(const float4*)(gsrc + kbase);

            #pragma unroll 1
            for (int s = 0; s < 10; ++s) {
                *(float4*)ldst = av;
                __syncthreads();
                if (s < 9) av = *(const float4*)(gsrc + kbase + (s + 1) * 64);
                #pragma unroll
                for (int ks = 0; ks < 2; ++ks) {
                    bf16x8 a = *(const bf16x8*)(As + (wm * 16 + lm) * 72 + ks * 32 + kb * 8);
                    bf16x8 bb = *(const bf16x8*)(Bs + (wn * 16 + lm) * 72 + ks * 32 + kb * 8);
                    acc = __builtin_amdgcn_mfma_f32_16x16x32_bf16(a, bb, acc, 0, 0, 0);
                }
                __syncthreads();
            }

            const int mrow = m0 + wm * 16 + kb * 4;
            const int ncol = n0 + wn * 16 + lm;
            #pragma unroll
            for (int rg = 0; rg < 4; ++rg)
                Cpart[((size_t)z * SBN + mrow + rg) * HD + ncol] = acc[rg];
        }

        grid.sync();

        // ================= Phase C: fused MLP heads =================
        {
            float* hsh = (float*)arena;           // 512 f
            float* h2b = (float*)(arena + 2048);  // 2*256 f
            float* res = (float*)(arena + 4096);  // 4 f

            if (t < 512) {
                float s = 0.f;
                #pragma unroll
                for (int z = 0; z < SPLITK; ++z)
                    s += Cpart[((size_t)z * SBN + ib) * HD + t];
                hsh[t] = fmaxf(fmaf(s, inv_denom[ib], b1[t]), 0.f);
            }
            __syncthreads();

            if (t < 512) {
                int head = t >> 8, col = t & 255;
                const uint4* Wr = (const uint4*)(WhidT + (size_t)(head * 256 + col) * 512);
                float bias = head ? bs1[col] : bm1[col];
                float a = 0.f;
                #pragma unroll 8
                for (int u = 0; u < 64; ++u) {
                    uint4 wv = Wr[u];
                    const float* hp = &hsh[u * 8];
                    a = fmaf(hp[0], bf2f_lo(wv.x), a);
                    a = fmaf(hp[1], bf2f_hi(wv.x), a);
                    a = fmaf(hp[2], bf2f_lo(wv.y), a);
                    a = fmaf(hp[3], bf2f_hi(wv.y), a);
                    a = fmaf(hp[4], bf2f_lo(wv.z), a);
                    a = fmaf(hp[5], bf2f_hi(wv.z), a);
                    a = fmaf(hp[6], bf2f_lo(wv.w), a);
                    a = fmaf(hp[7], bf2f_hi(wv.w), a);
                }
                h2b[head * 256 + col] = fmaxf(a + bias, 0.f);
            }
            __syncthreads();

            {
                int w = t >> 6, l = t & 63;
                if (w < 4) {
                    int zd = (w >> 1) & 1, head = w & 1;
                    const float* W2 = head ? Ws2 : Wm2;
                    float a = 0.f;
                    #pragma unroll
                    for (int u = 0; u < 4; ++u) {
                        int i = l + u * 64;
                        a = fmaf(h2b[head * 256 + i], W2[i * 2 + zd], a);
                    }
                    #pragma unroll
                    for (int off = 32; off > 0; off >>= 1) a += __shfl_down(a, off, 64);
                    if (l == 0) {
                        float r = head ? __expf(a + bs2[zd]) : tanhf(a + bm2[zd]);
                        res[zd * 2 + head] = r;
                    }
                }
            }
            __syncthreads();
            if (t < 2) {
                int zd = t;
                float mean = res[zd * 2 + 0];
                float stdv = res[zd * 2 + 1];
                float ev = eps[(size_t)ib * 6 + k * 2 + zd];
                float z = fmaf(stdv, ev, mean);
                int oidx = ib * 6 + k * 2 + zd;
                out[oidx]        = mean;   // q_mean
                out[1536 + oidx] = stdv;   // q_std
                out[3072 + oidx] = z;      // z_where
                z_cur[ib * 2 + zd] = z;
            }
            __syncthreads();   // arena reused by next k's conv
        }
    }
}

// ---------------------------------------------------------------------------
extern "C" void kernel_launch(void* const* d_in, const int* in_sizes, int n_in,
                              void* d_out, int out_size, void* d_ws, size_t ws_size,
                              hipStream_t stream)
{
    const float* frames = (const float*)d_in[0];
    const float* ck     = (const float*)d_in[1];
    const float* eps    = (const float*)d_in[2];
    const float* W1     = (const float*)d_in[3];
    const float* b1     = (const float*)d_in[4];
    const float* Wm1    = (const float*)d_in[5];
    const float* bm1    = (const float*)d_in[6];
    const float* Wm2    = (const float*)d_in[7];
    const float* bm2    = (const float*)d_in[8];
    const float* Ws1    = (const float*)d_in[9];
    const float* bs1    = (const float*)d_in[10];
    const float* Ws2    = (const float*)d_in[11];
    const float* bs2    = (const float*)d_in[12];
    const int*   tsp    = (const int*)d_in[13];
    float* out = (float*)d_out;

    float* frameL  = (float*)d_ws;                   // 2359296 f
    float* Cpart   = frameL + 2359296;               // 8*256*512 = 1048576 f
    float* inv_den = Cpart + 1048576;                // 256 f
    float* z_cur   = inv_den + 256;                  // 512 f
    ushort* e_buf  = (ushort*)(z_cur + 512);         // 256*KPAD
    ushort* W1T    = e_buf + (size_t)SBN * KPAD;     // 512*KPAD
    ushort* WhidT  = W1T + (size_t)HD * KPAD;        // 512*512

    void* args[] = {
        (void*)&frames, (void*)&ck, (void*)&eps, (void*)&W1, (void*)&b1,
        (void*)&Wm1, (void*)&bm1, (void*)&Wm2, (void*)&bm2,
        (void*)&Ws1, (void*)&bs1, (void*)&Ws2, (void*)&bs2,
        (void*)&tsp, (void*)&out,
        (void*)&frameL, (void*)&Cpart, (void*)&inv_den, (void*)&z_cur,
        (void*)&e_buf, (void*)&W1T, (void*)&WhidT
    };
    hipLaunchCooperativeKernel((const void*)mega_kernel,
                               dim3(SBN), dim3(1024), args, 0, stream);
}

// Round 9
// 308.062 us; speedup vs baseline: 1.6941x; 1.6941x over previous
//
#include <hip/hip_runtime.h>
#include <hip/hip_bf16.h>
#include <math.h>

// Problem constants
#define FPD 96      // frame size
#define DPD 28      // digit/kernel size
#define CPD 69      // FPD - DPD + 1
#define NPD 4761    // CPD*CPD
#define KKC 3       // K iterations
#define SBN 256     // S*B images
#define TT 8        // T
#define HD 512      // H
#define KPAD 4768   // 149*32, padded K for MFMA GEMM
#define SPLITK 15
#define FRSH 104    // frame LDS row stride (halfs)
#define CVS 76      // cv slab row stride (floats)

typedef __attribute__((ext_vector_type(8))) short bf16x8;
typedef __attribute__((ext_vector_type(4))) float f32x4;
typedef _Float16 half_t;
typedef __attribute__((ext_vector_type(2))) _Float16 half2_t;

__device__ __forceinline__ float bf2f_lo(unsigned int u) {
    union { unsigned int i; float f; } v; v.i = u << 16; return v.f;
}
__device__ __forceinline__ float bf2f_hi(unsigned int u) {
    union { unsigned int i; float f; } v; v.i = u & 0xffff0000u; return v.f;
}
__device__ __forceinline__ half2_t u2h(unsigned int u) {
    union { unsigned int i; half2_t h; } v; v.i = u; return v.h;
}

// ---------------------------------------------------------------------------
// Weight prep (one dispatch): blocks 0..599 build W1T (bf16, KPAD-padded,
// [n][k]); blocks 600..663 build WhidT ([head*256+col][i], i contiguous).
__global__ __launch_bounds__(256) void wprep_kernel(
    const float* __restrict__ W1, const float* __restrict__ Wm1,
    const float* __restrict__ Ws1,
    ushort* __restrict__ W1T, ushort* __restrict__ WhidT)
{
    __shared__ ushort tile[64][65];
    const int t = threadIdx.x;
    const int ln = t & 63;
    const int lr = t >> 6;             // 0..3
    const int b = blockIdx.x;

    if (b < 600) {
        const int k0 = (b % 75) * 64;
        const int n0 = (b / 75) * 64;
        #pragma unroll
        for (int i = 0; i < 16; ++i) {
            int kk = k0 + lr + i * 4;
            float v = (kk < NPD) ? W1[(size_t)kk * HD + n0 + ln] : 0.f;
            __hip_bfloat16 h = __float2bfloat16(v);
            tile[lr + i * 4][ln] = *reinterpret_cast<ushort*>(&h);
        }
        __syncthreads();
        #pragma unroll
        for (int i = 0; i < 16; ++i) {
            int nn = lr + i * 4;
            int kk = k0 + ln;
            if (kk < KPAD)
                W1T[(size_t)(n0 + nn) * KPAD + kk] = tile[ln][nn];
        }
    } else {
        const int bb = b - 600;
        const int i0 = (bb & 7) * 64;
        const int r0 = (bb >> 3) * 64;
        #pragma unroll
        for (int rep = 0; rep < 16; ++rep) {
            int i = i0 + lr + rep * 4;
            int r = r0 + ln;
            const float* src = (r >= 256) ? Ws1 : Wm1;
            float v = src[(size_t)i * 256 + (r & 255)];
            __hip_bfloat16 h = __float2bfloat16(v);
            tile[lr + rep * 4][ln] = *reinterpret_cast<ushort*>(&h);
        }
        __syncthreads();
        #pragma unroll
        for (int rep = 0; rep < 16; ++rep) {
            int r = r0 + lr + rep * 4;
            WhidT[(size_t)r * 512 + i0 + ln] = tile[ln][lr + rep * 4];
        }
    }
}

// ---------------------------------------------------------------------------
// Conv (f16 dot2) + fused recon-subtract + softmax-exp (bf16 out).
// One block (512 threads, launch_bounds(512,2) -> 256-VGPR budget, no spills)
// per image. Tasks: 2 dy-halves x 3 tiles(24 wide) x 69 oy = 414.
__global__ __launch_bounds__(512, 2) void conv_softmax_kernel(
    const float* __restrict__ frames, const int* __restrict__ tsp,
    float* __restrict__ frameL, const float* __restrict__ ck,
    const float* __restrict__ z_cur,
    ushort* __restrict__ e_buf, float* __restrict__ inv_denom, int k)
{
    __shared__ __align__(16) half_t fr[96 * FRSH];
    __shared__ __align__(16) half_t kr[28 * 32];   // rows padded to 32 halfs
    __shared__ float dg[784];
    __shared__ __align__(16) float cv[2][69 * CVS];
    __shared__ float red[16];

    const int t = threadIdx.x;
    const int ib = blockIdx.x;

    for (int i = t; i < 28 * 32; i += 512) {
        int dy = i >> 5, dx = i & 31;
        float v = (dx < 28) ? ck[((size_t)ib * KKC + k) * 784 + dy * 28 + dx] : 0.f;
        kr[i] = (half_t)v;
    }
    if (k > 0)
        for (int i = t; i < 784; i += 512)
            dg[i] = ck[((size_t)ib * KKC + (k - 1)) * 784 + i];
    float zx = 0.f, zy = 0.f;
    if (k > 0) { zx = z_cur[ib * 2]; zy = z_cur[ib * 2 + 1]; }
    __syncthreads();

    const float* src = (k < 2)
        ? frames + ((size_t)ib * TT + *tsp) * 9216
        : frameL + (size_t)ib * 9216;
    const float scale = 96.f / 28.f;
    for (int p = t; p < 9216; p += 512) {
        int r = p / 96, c = p - r * 96;
        float val = src[p];
        if (k > 0) {
            float oci = (2.f * r + 1.f) / 96.f - 1.f;
            float ocj = (2.f * c + 1.f) / 96.f - 1.f;
            float py = ((scale * (oci - zy) + 1.f) * 28.f - 1.f) * 0.5f;
            float px = ((scale * (ocj - zx) + 1.f) * 28.f - 1.f) * 0.5f;
            float py0f = floorf(py), px0f = floorf(px);
            float fy = py - py0f, fx = px - px0f;
            int y0 = (int)py0f, x0 = (int)px0f;
            int y1 = y0 + 1, x1 = x0 + 1;
            float wy0 = (y0 >= 0 && y0 < DPD) ? 1.f - fy : 0.f;
            float wy1 = (y1 >= 0 && y1 < DPD) ? fy : 0.f;
            float wx0 = (x0 >= 0 && x0 < DPD) ? 1.f - fx : 0.f;
            float wx1 = (x1 >= 0 && x1 < DPD) ? fx : 0.f;
            int y0c = min(max(y0, 0), DPD - 1), y1c = min(max(y1, 0), DPD - 1);
            int x0c = min(max(x0, 0), DPD - 1), x1c = min(max(x1, 0), DPD - 1);
            float tmp0 = wy0 * dg[y0c * DPD + x0c] + wy1 * dg[y1c * DPD + x0c];
            float tmp1 = wy0 * dg[y0c * DPD + x1c] + wy1 * dg[y1c * DPD + x1c];
            val -= wx0 * tmp0 + wx1 * tmp1;
        }
        fr[r * FRSH + c] = (half_t)val;
        if (k == 1) frameL[(size_t)ib * 9216 + p] = val;
    }
    for (int i = t; i < 96 * 8; i += 512)
        fr[(i >> 3) * FRSH + 96 + (i & 7)] = (half_t)0.f;   // pad cols 96..103
    __syncthreads();

    if (t < 414) {
        const int half = t / 207;
        const int rem  = t - half * 207;
        const int tile = rem / 69;
        const int oy   = rem - tile * 69;
        const int ox0  = tile * 24;
        const int dy0  = half * 14;

        float acc[24];
        #pragma unroll
        for (int j = 0; j < 24; ++j) acc[j] = 0.f;

        #pragma unroll 1
        for (int dd = 0; dd < 14; ++dd) {
            const int dy = dy0 + dd;
            const unsigned int* frow = (const unsigned int*)&fr[(oy + dy) * FRSH + ox0];
            const unsigned int* krow = (const unsigned int*)&kr[dy * 32];
            unsigned int W[28], K[16], V[25];
            #pragma unroll
            for (int u = 0; u < 7; ++u) {
                uint4 v = *(const uint4*)(frow + 4 * u);
                W[4*u] = v.x; W[4*u+1] = v.y; W[4*u+2] = v.z; W[4*u+3] = v.w;
            }
            #pragma unroll
            for (int u = 0; u < 4; ++u) {
                uint4 v = *(const uint4*)(krow + 4 * u);
                K[4*u] = v.x; K[4*u+1] = v.y; K[4*u+2] = v.z; K[4*u+3] = v.w;
            }
            #pragma unroll
            for (int i = 0; i < 25; ++i)
                V[i] = (W[i] >> 16) | (W[i + 1] << 16);
            #pragma unroll
            for (int m = 0; m < 12; ++m) {
                float ae = acc[2*m], ao = acc[2*m+1];
                #pragma unroll
                for (int i = 0; i < 14; ++i) {
                    ae = __builtin_amdgcn_fdot2(u2h(W[m + i]), u2h(K[i]), ae, false);
                    ao = __builtin_amdgcn_fdot2(u2h(V[m + i]), u2h(K[i]), ao, false);
                }
                acc[2*m] = ae; acc[2*m+1] = ao;
            }
        }
        float* cvq = &cv[half][oy * CVS + ox0];
        #pragma unroll
        for (int u = 0; u < 6; ++u) {
            float4 v = make_float4(acc[4*u], acc[4*u+1], acc[4*u+2], acc[4*u+3]);
            *(float4*)(cvq + 4 * u) = v;
        }
    }
    __syncthreads();

    // merge halves + block max (stride-76 slabs; skip pad cols)
    float m = -INFINITY;
    for (int p = t; p < 69 * CVS; p += 512) {
        int ox = p - (p / CVS) * CVS;
        if (ox < CPD) {
            float v = cv[0][p] + cv[1][p];
            cv[0][p] = v;
            m = fmaxf(m, v);
        }
    }
    #pragma unroll
    for (int off = 32; off > 0; off >>= 1) m = fmaxf(m, __shfl_down(m, off, 64));
    int lane = t & 63, wid = t >> 6;
    if (lane == 0) red[wid] = m;
    __syncthreads();
    m = red[0];
    #pragma unroll
    for (int i = 1; i < 8; ++i) m = fmaxf(m, red[i]);

    float s = 0.f;
    ushort* eo = e_buf + (size_t)ib * KPAD;
    for (int p = t; p < 69 * CVS; p += 512) {
        int oy = p / CVS;
        int ox = p - oy * CVS;
        if (ox < CPD) {
            float ev = __expf(cv[0][p] - m);
            __hip_bfloat16 h = __float2bfloat16(ev);
            eo[oy * CPD + ox] = *reinterpret_cast<ushort*>(&h);
            s += ev;
        }
    }
    #pragma unroll
    for (int off = 32; off > 0; off >>= 1) s += __shfl_down(s, off, 64);
    if (lane == 0) red[8 + wid] = s;
    __syncthreads();
    if (t == 0) {
        float tot = 0.f;
        #pragma unroll
        for (int i = 0; i < 8; ++i) tot += red[8 + i];
        inv_denom[ib] = 1.0f / tot;
    }
    if (t < KPAD - NPD) eo[NPD + t] = 0;   // zero k-padding
}

// ---------------------------------------------------------------------------
// Cpart[z] = E(256xKPAD bf16) @ W1T^T (KPADx512 bf16), split-K=15, MFMA.
__global__ __launch_bounds__(256) void gemm1_mfma(
    const ushort* __restrict__ E, const ushort* __restrict__ W1T,
    float* __restrict__ Cpart)
{
    __shared__ __align__(16) ushort As[64][56];   // [m][k]
    __shared__ __align__(16) ushort Bs[64][56];   // [n][k]

    const int t  = threadIdx.x;
    const int m0 = blockIdx.x * 64;   // 4
    const int n0 = blockIdx.y * 64;   // 8
    const int z  = blockIdx.z;        // 15
    const int step0 = z * 10;
    const int nstep = min(10, 149 - step0);   // z=14 -> 9

    const int r = t >> 2;             // 0..63
    const int c = t & 3;              // 0..3
    const int l = t & 63;
    const int w = t >> 6;             // wave 0..3
    const int lm = l & 15;
    const int kb = l >> 4;            // 0..3

    f32x4 zero = {0.f, 0.f, 0.f, 0.f};
    f32x4 acc[4] = {zero, zero, zero, zero};

    const ushort* eA = E   + (size_t)(m0 + r) * KPAD + c * 8;
    const ushort* eB = W1T + (size_t)(n0 + r) * KPAD + c * 8;

    int k0 = step0 * 32;
    float4 av = *(const float4*)(eA + k0);
    float4 bv = *(const float4*)(eB + k0);

    for (int s = 0; s < nstep; ++s) {
        *(float4*)&As[r][c * 8] = av;
        *(float4*)&Bs[r][c * 8] = bv;
        __syncthreads();
        if (s + 1 < nstep) {
            int kn = (step0 + s + 1) * 32;
            av = *(const float4*)(eA + kn);
            bv = *(const float4*)(eB + kn);
        }
        bf16x8 a = *(const bf16x8*)&As[w * 16 + lm][kb * 8];
        #pragma unroll
        for (int j = 0; j < 4; ++j) {
            bf16x8 b = *(const bf16x8*)&Bs[j * 16 + lm][kb * 8];
            acc[j] = __builtin_amdgcn_mfma_f32_16x16x32_bf16(a, b, acc[j], 0, 0, 0);
        }
        __syncthreads();
    }

    // C/D layout: col = lane&15 (n), row = (lane>>4)*4 + reg (m)
    const int mrow = m0 + w * 16 + kb * 4;
    #pragma unroll
    for (int j = 0; j < 4; ++j) {
        int n = n0 + j * 16 + lm;
        #pragma unroll
        for (int rg = 0; rg < 4; ++rg)
            Cpart[((size_t)z * SBN + mrow + rg) * HD + n] = acc[j][rg];
    }
}

// ---------------------------------------------------------------------------
// Fused MLP: h = relu(sum_z Cpart * inv_den + b1); hidden (bf16, K-contiguous
// WhidT rows, 16B vector loads); heads. 256 blocks x 512 threads, 1 image.
__global__ __launch_bounds__(512) void mlp_fused(
    const float* __restrict__ Cpart, const float* __restrict__ inv_denom,
    const float* __restrict__ b1, const ushort* __restrict__ WhidT,
    const float* __restrict__ bm1, const float* __restrict__ bs1,
    const float* __restrict__ Wm2, const float* __restrict__ bm2,
    const float* __restrict__ Ws2, const float* __restrict__ bs2,
    const float* __restrict__ eps, float* __restrict__ out,
    float* __restrict__ z_cur, int k)
{
    __shared__ float hsh[HD];
    __shared__ float h2[2][256];       // [head][col]
    __shared__ float res_sh[2][2];     // [zd][head]

    const int t = threadIdx.x;
    const int ib = blockIdx.x;

    {
        float s = 0.f;
        #pragma unroll
        for (int z = 0; z < SPLITK; ++z)
            s += Cpart[((size_t)z * SBN + ib) * HD + t];
        hsh[t] = fmaxf(fmaf(s, inv_denom[ib], b1[t]), 0.f);
    }
    __syncthreads();

    {
        int head = t >> 8, col = t & 255;
        const uint4* Wr = (const uint4*)(WhidT + (size_t)(head * 256 + col) * 512);
        float bias = head ? bs1[col] : bm1[col];
        float a = 0.f;
        #pragma unroll 8
        for (int u = 0; u < 64; ++u) {
            uint4 wv = Wr[u];
            const float* hp = &hsh[u * 8];
            a = fmaf(hp[0], bf2f_lo(wv.x), a);
            a = fmaf(hp[1], bf2f_hi(wv.x), a);
            a = fmaf(hp[2], bf2f_lo(wv.y), a);
            a = fmaf(hp[3], bf2f_hi(wv.y), a);
            a = fmaf(hp[4], bf2f_lo(wv.z), a);
            a = fmaf(hp[5], bf2f_hi(wv.z), a);
            a = fmaf(hp[6], bf2f_lo(wv.w), a);
            a = fmaf(hp[7], bf2f_hi(wv.w), a);
        }
        h2[head][col] = fmaxf(a + bias, 0.f);
    }
    __syncthreads();

    {
        int w = t >> 6, l = t & 63;
        if (w < 4) {
            int zd = (w >> 1) & 1, head = w & 1;
            const float* W2 = head ? Ws2 : Wm2;
            float a = 0.f;
            #pragma unroll
            for (int u = 0; u < 4; ++u) {
                int i = l + u * 64;
                a = fmaf(h2[head][i], W2[i * 2 + zd], a);
            }
            #pragma unroll
            for (int off = 32; off > 0; off >>= 1) a += __shfl_down(a, off, 64);
            if (l == 0) {
                float r = head ? __expf(a + bs2[zd]) : tanhf(a + bm2[zd]);
                res_sh[zd][head] = r;
            }
        }
    }
    __syncthreads();
    if (t < 2) {
        int zd = t;
        float mean = res_sh[zd][0];
        float stdv = res_sh[zd][1];
        float ev = eps[(size_t)ib * 6 + k * 2 + zd];
        float z = fmaf(stdv, ev, mean);
        int oidx = ib * 6 + k * 2 + zd;
        out[oidx]        = mean;   // q_mean
        out[1536 + oidx] = stdv;   // q_std
        out[3072 + oidx] = z;      // z_where
        z_cur[ib * 2 + zd] = z;
    }
}

// ---------------------------------------------------------------------------
extern "C" void kernel_launch(void* const* d_in, const int* in_sizes, int n_in,
                              void* d_out, int out_size, void* d_ws, size_t ws_size,
                              hipStream_t stream)
{
    const float* frames = (const float*)d_in[0];
    const float* ck     = (const float*)d_in[1];
    const float* eps    = (const float*)d_in[2];
    const float* W1     = (const float*)d_in[3];
    const float* b1     = (const float*)d_in[4];
    const float* Wm1    = (const float*)d_in[5];
    const float* bm1    = (const float*)d_in[6];
    const float* Wm2    = (const float*)d_in[7];
    const float* bm2    = (const float*)d_in[8];
    const float* Ws1    = (const float*)d_in[9];
    const float* bs1    = (const float*)d_in[10];
    const float* Ws2    = (const float*)d_in[11];
    const float* bs2    = (const float*)d_in[12];
    const int*   tsp    = (const int*)d_in[13];
    float* out = (float*)d_out;

    float* frameL  = (float*)d_ws;                   // 2359296 f
    float* Cpart   = frameL + 2359296;               // 15*256*512 = 1966080 f
    float* inv_den = Cpart + 1966080;                // 256 f
    float* z_cur   = inv_den + 256;                  // 512 f
    ushort* e_buf  = (ushort*)(z_cur + 512);         // 256*KPAD
    ushort* W1T    = e_buf + (size_t)SBN * KPAD;     // 512*KPAD
    ushort* WhidT  = W1T + (size_t)HD * KPAD;        // 512*512

    wprep_kernel<<<664, 256, 0, stream>>>(W1, Wm1, Ws1, W1T, WhidT);

    for (int k = 0; k < KKC; ++k) {
        conv_softmax_kernel<<<256, 512, 0, stream>>>(
            frames, tsp, frameL, ck, z_cur, e_buf, inv_den, k);
        gemm1_mfma<<<dim3(4, 8, SPLITK), 256, 0, stream>>>(e_buf, W1T, Cpart);
        mlp_fused<<<256, 512, 0, stream>>>(Cpart, inv_den, b1, WhidT,
                                           bm1, bs1, Wm2, bm2, Ws2, bs2,
                                           eps, out, z_cur, k);
    }
}